// Round 1
// baseline (1817.182 us; speedup 1.0000x reference)
//
#include <hip/hip_runtime.h>

typedef __bf16 bf16;
typedef bf16 bf16x8 __attribute__((ext_vector_type(8)));
typedef float f32x4 __attribute__((ext_vector_type(4)));

#define Vv 32000
#define Ee 512
#define Hh 1024
#define Bb 64
#define Ssz 64
#define Tt 32
#define TBm 2048
#define FFc 2048
#define G3c 3072

__device__ __forceinline__ float sigm(float x) { return 1.f / (1.f + expf(-x)); }

__global__ void cvt_simple_k(const float* __restrict__ s, bf16* __restrict__ d, int n) {
  int stride = gridDim.x * blockDim.x;
  for (int i = blockIdx.x * blockDim.x + threadIdx.x; i < n; i += stride)
    d[i] = (bf16)s[i];
}

__global__ void cvt_split_k(const float* __restrict__ s, bf16* __restrict__ hi,
                            bf16* __restrict__ lo, int n) {
  int stride = gridDim.x * blockDim.x;
  for (int i = blockIdx.x * blockDim.x + threadIdx.x; i < n; i += stride) {
    float v = s[i];
    bf16 h = (bf16)v;
    hi[i] = h;
    lo[i] = (bf16)(v - (float)h);
  }
}

// src[R][C] f32 -> dst[C][R] bf16
__global__ void transpose_cvt_k(const float* __restrict__ src, bf16* __restrict__ dst,
                                int R, int C) {
  __shared__ float tile[32][33];
  int bx = blockIdx.x * 32;  // C offset
  int by = blockIdx.y * 32;  // R offset
  int tx = threadIdx.x & 31, ty = threadIdx.x >> 5;
#pragma unroll
  for (int i = 0; i < 4; ++i) {
    int r = ty + i * 8;
    tile[r][tx] = src[(size_t)(by + r) * C + bx + tx];
  }
  __syncthreads();
#pragma unroll
  for (int i = 0; i < 4; ++i) {
    int r = ty + i * 8;
    dst[(size_t)(bx + r) * R + by + tx] = (bf16)tile[tx][r];
  }
}

__global__ void embed_k(const float* __restrict__ emb, const int* __restrict__ label,
                        bf16* __restrict__ xe) {
  int m = blockIdx.x;          // m = t*64 + b
  int t = m >> 6, b = m & 63;
  int tok = (t == 0) ? 1 : label[b * Tt + t - 1];
  const float* src = emb + (size_t)tok * Ee;
  bf16* dst = xe + (size_t)m * Ee;
  for (int e = threadIdx.x; e < Ee; e += blockDim.x) dst[e] = (bf16)src[e];
}

// C[m,n] = sum_k A[m,k]*Bt[n,k] + bias[n]; NT layout, bf16 in, f32 out.
// MODE 0: plain write  MODE 1: ELU  MODE 2: scatter to d_out[b*T*V + t*V + n]
template <int MODE>
__global__ void __launch_bounds__(256) gemm_nt_k(
    const bf16* __restrict__ A, const bf16* __restrict__ Bt,
    const float* __restrict__ bias, float* __restrict__ C,
    int M, int N, int K) {
  __shared__ bf16 As[128 * 32];
  __shared__ bf16 Bs[128 * 32];
  const int tid = threadIdx.x;
  const int wv = tid >> 6, ln = tid & 63;
  const int wr = wv >> 1, wc = wv & 1;
  const int l15 = ln & 15, l4 = ln >> 4;
  const int m0 = blockIdx.y * 128, n0 = blockIdx.x * 128;

  const f32x4 vzero = {0.f, 0.f, 0.f, 0.f};
  f32x4 acc[4][4];
#pragma unroll
  for (int i = 0; i < 4; ++i) {
#pragma unroll
    for (int j = 0; j < 4; ++j) acc[i][j] = vzero;
  }

  const int nk = K >> 5;
  for (int kt = 0; kt < nk; ++kt) {
    const int k0 = kt << 5;
    __syncthreads();
#pragma unroll
    for (int it = 0; it < 2; ++it) {
      int c = tid + it * 256;
      int row = c >> 2, kc = (c & 3) << 3;
      *(uint4*)&As[row * 32 + kc] = *(const uint4*)(A + (size_t)(m0 + row) * K + k0 + kc);
      *(uint4*)&Bs[row * 32 + kc] = *(const uint4*)(Bt + (size_t)(n0 + row) * K + k0 + kc);
    }
    __syncthreads();
    bf16x8 af[4], bfv[4];
#pragma unroll
    for (int mt = 0; mt < 4; ++mt)
      af[mt] = *(const bf16x8*)&As[(wr * 64 + mt * 16 + l15) * 32 + l4 * 8];
#pragma unroll
    for (int nt = 0; nt < 4; ++nt)
      bfv[nt] = *(const bf16x8*)&Bs[(wc * 64 + nt * 16 + l15) * 32 + l4 * 8];
#pragma unroll
    for (int mt = 0; mt < 4; ++mt) {
#pragma unroll
      for (int nt = 0; nt < 4; ++nt)
        acc[mt][nt] = __builtin_amdgcn_mfma_f32_16x16x32_bf16(af[mt], bfv[nt], acc[mt][nt], 0, 0, 0);
    }
  }

#pragma unroll
  for (int mt = 0; mt < 4; ++mt) {
#pragma unroll
    for (int nt = 0; nt < 4; ++nt) {
      int col = wc * 64 + nt * 16 + l15;
      int n = n0 + col;
      float bv = bias[n];
#pragma unroll
      for (int r = 0; r < 4; ++r) {
        int row = wr * 64 + mt * 16 + l4 * 4 + r;
        int m = m0 + row;
        float v = acc[mt][nt][r] + bv;
        if (MODE == 1) v = (v > 0.f) ? v : expm1f(v);
        if (MODE == 2) {
          size_t idx = (size_t)(m & 63) * ((size_t)Tt * Vv) + (size_t)(m >> 6) * Vv + (size_t)n;
          C[idx] = v;
        } else {
          C[(size_t)m * N + n] = v;
        }
      }
    }
  }
}

// One GRU step: gh = h @ w_hh^T (split-bf16, 3 MFMAs per product for ~fp32
// accuracy), then fused gate math. 64 blocks x 256: block owns 16 j-cols,
// wave wv owns b-rows [wv*16, wv*16+16).
__global__ void __launch_bounds__(256) gru_step_k(
    const bf16* __restrict__ hhi, const bf16* __restrict__ hlo,
    const bf16* __restrict__ whhHi, const bf16* __restrict__ whhLo,
    const float* __restrict__ gates, const float* __restrict__ bhh,
    const float* __restrict__ hprev, float* __restrict__ hseq_t,
    bf16* __restrict__ nhi, bf16* __restrict__ nlo, int t) {
  const int tid = threadIdx.x;
  const int wv = tid >> 6, ln = tid & 63;
  const int l15 = ln & 15, l4 = ln >> 4;
  const int j0 = blockIdx.x * 16;
  const int brow = wv * 16;

  const f32x4 vzero = {0.f, 0.f, 0.f, 0.f};
  f32x4 acc[3] = {vzero, vzero, vzero};
  const int b_a = brow + l15;
#pragma unroll 2
  for (int kk = 0; kk < 32; ++kk) {
    int k = kk * 32 + l4 * 8;
    bf16x8 ahi = *(const bf16x8*)(hhi + (size_t)b_a * Hh + k);
    bf16x8 alo = *(const bf16x8*)(hlo + (size_t)b_a * Hh + k);
#pragma unroll
    for (int g = 0; g < 3; ++g) {
      size_t nrow = (size_t)(g * Hh + j0 + l15) * Hh + k;
      bf16x8 bhi = *(const bf16x8*)(whhHi + nrow);
      bf16x8 blo = *(const bf16x8*)(whhLo + nrow);
      acc[g] = __builtin_amdgcn_mfma_f32_16x16x32_bf16(ahi, bhi, acc[g], 0, 0, 0);
      acc[g] = __builtin_amdgcn_mfma_f32_16x16x32_bf16(ahi, blo, acc[g], 0, 0, 0);
      acc[g] = __builtin_amdgcn_mfma_f32_16x16x32_bf16(alo, bhi, acc[g], 0, 0, 0);
    }
  }
  int j = j0 + l15;
  float bhr = bhh[j], bhz = bhh[Hh + j], bhn = bhh[2 * Hh + j];
#pragma unroll
  for (int r = 0; r < 4; ++r) {
    int b = brow + l4 * 4 + r;
    const float* gx = gates + (size_t)(t * Bb + b) * G3c;
    float rg = sigm(gx[j] + acc[0][r] + bhr);
    float zg = sigm(gx[Hh + j] + acc[1][r] + bhz);
    float ng = tanhf(gx[2 * Hh + j] + rg * (acc[2][r] + bhn));
    float hp = hprev[(size_t)b * Hh + j];
    float hv = (1.f - zg) * ng + zg * hp;
    hseq_t[(size_t)b * Hh + j] = hv;
    bf16 hb = (bf16)hv;
    nhi[(size_t)b * Hh + j] = hb;
    nlo[(size_t)b * Hh + j] = (bf16)(hv - (float)hb);
  }
}

// dot attention + feat=concat(h,ctx). One block per (t,b).
__global__ void __launch_bounds__(256) attn_k(
    const float* __restrict__ hseq, const float* __restrict__ enc,
    float* __restrict__ feat) {
  __shared__ float red[256];
  __shared__ float wsm[Ssz];
  int m = blockIdx.x;
  int t = m >> 6, b = m & 63;
  const float* hv = hseq + (size_t)t * Bb * Hh + (size_t)b * Hh;
  const float* eb = enc + (size_t)b * Ssz * Hh;
  int tid = threadIdx.x;
  int s = tid >> 2, q = tid & 3;
  const float* er = eb + (size_t)s * Hh + q * 256;
  const float* hq = hv + q * 256;
  float p = 0.f;
#pragma unroll 4
  for (int i = 0; i < 256; i += 4) {
    float4 a = *(const float4*)(hq + i);
    float4 c = *(const float4*)(er + i);
    p += a.x * c.x + a.y * c.y + a.z * c.z + a.w * c.w;
  }
  red[tid] = p;
  __syncthreads();
  if (tid < 64) {
    float sc = red[tid * 4] + red[tid * 4 + 1] + red[tid * 4 + 2] + red[tid * 4 + 3];
    float mx = sc;
#pragma unroll
    for (int off = 32; off > 0; off >>= 1) mx = fmaxf(mx, __shfl_xor(mx, off));
    float e = expf(sc - mx);
    float sm = e;
#pragma unroll
    for (int off = 32; off > 0; off >>= 1) sm += __shfl_xor(sm, off);
    wsm[tid] = e / sm;
  }
  __syncthreads();
  float* fr = feat + (size_t)m * FFc;
  for (int h = tid; h < Hh; h += 256) {
    float a = 0.f;
#pragma unroll 8
    for (int si = 0; si < Ssz; ++si) a = fmaf(wsm[si], eb[(size_t)si * Hh + h], a);
    fr[Hh + h] = a;
    fr[h] = hv[h];
  }
}

// training-mode BN over batch dim (per t). grid (CH/256, T)
__global__ void __launch_bounds__(256) bn_k(
    const float* __restrict__ x, const float* __restrict__ gam,
    const float* __restrict__ bet, bf16* __restrict__ y, int CH) {
  int t = blockIdx.y;
  int c = blockIdx.x * 256 + threadIdx.x;
  const float* xp = x + (size_t)t * Bb * CH + c;
  float v[Bb];
  float s = 0.f, ss = 0.f;
#pragma unroll
  for (int b = 0; b < Bb; ++b) {
    float u = xp[(size_t)b * CH];
    v[b] = u;
    s += u;
    ss += u * u;
  }
  float mean = s * (1.f / Bb);
  float var = ss * (1.f / Bb) - mean * mean;
  float inv = rsqrtf(var + 1e-5f);
  float sc = gam[c] * inv;
  float sh = bet[c] - mean * sc;
  bf16* yp = y + (size_t)t * Bb * CH + c;
#pragma unroll
  for (int b = 0; b < Bb; ++b) yp[(size_t)b * CH] = (bf16)(v[b] * sc + sh);
}

// in-place row softmax over V. block per (t,b) row of d_out.
__global__ void __launch_bounds__(256) softmax_k(float* __restrict__ out) {
  __shared__ float rm[256], rs[256];
  int m = blockIdx.x;
  int t = m >> 6, b = m & 63;
  float* row = out + (size_t)b * Tt * Vv + (size_t)t * Vv;
  int tid = threadIdx.x;
  float mx = -3.0e38f, sm = 0.f;
  for (int i = tid * 4; i < Vv; i += 1024) {
    float4 v = *(const float4*)(row + i);
    float m4 = fmaxf(fmaxf(v.x, v.y), fmaxf(v.z, v.w));
    if (m4 > mx) { sm *= expf(mx - m4); mx = m4; }
    sm += expf(v.x - mx) + expf(v.y - mx) + expf(v.z - mx) + expf(v.w - mx);
  }
  rm[tid] = mx;
  rs[tid] = sm;
  __syncthreads();
  for (int off = 128; off > 0; off >>= 1) {
    if (tid < off) {
      float ma = rm[tid], mb = rm[tid + off];
      float m2 = fmaxf(ma, mb);
      rs[tid] = rs[tid] * expf(ma - m2) + rs[tid + off] * expf(mb - m2);
      rm[tid] = m2;
    }
    __syncthreads();
  }
  float M = rm[0];
  float inv = 1.f / rs[0];
  for (int i = tid * 4; i < Vv; i += 1024) {
    float4 v = *(const float4*)(row + i);
    v.x = expf(v.x - M) * inv;
    v.y = expf(v.y - M) * inv;
    v.z = expf(v.z - M) * inv;
    v.w = expf(v.w - M) * inv;
    *(float4*)(row + i) = v;
  }
}

__global__ void hlast_k(const float* __restrict__ src, float* __restrict__ dst) {
  int i = blockIdx.x * 256 + threadIdx.x;
  dst[i] = src[i];
}

extern "C" void kernel_launch(void* const* d_in, const int* in_sizes, int n_in,
                              void* d_out, int out_size, void* d_ws, size_t ws_size,
                              hipStream_t stream) {
  const float* enc   = (const float*)d_in[0];
  const int*   label = (const int*)d_in[1];
  const float* h0    = (const float*)d_in[2];
  // d_in[3] answer_lens: unused by the forward pass
  const float* emb   = (const float*)d_in[4];
  const float* w_ih  = (const float*)d_in[5];
  const float* w_hh  = (const float*)d_in[6];
  const float* b_ih  = (const float*)d_in[7];
  const float* b_hh  = (const float*)d_in[8];
  const float* bn1g  = (const float*)d_in[9];
  const float* bn1b  = (const float*)d_in[10];
  const float* W1    = (const float*)d_in[11];
  const float* b1    = (const float*)d_in[12];
  const float* bn2g  = (const float*)d_in[13];
  const float* bn2b  = (const float*)d_in[14];
  const float* W2    = (const float*)d_in[15];
  const float* b2    = (const float*)d_in[16];
  float* out = (float*)d_out;
  (void)in_sizes; (void)n_in; (void)out_size; (void)ws_size;

  char* ws = (char*)d_ws;
  size_t off = 0;
  auto alloc = [&](size_t bytes) -> void* {
    void* p = ws + off;
    off += (bytes + 255) & ~(size_t)255;
    return p;
  };
  bf16*  W2t   = (bf16*)alloc((size_t)Vv * Hh * 2);        // 64 MB
  bf16*  W1t   = (bf16*)alloc((size_t)Hh * FFc * 2);       // 4 MB
  bf16*  wihB  = (bf16*)alloc((size_t)G3c * Ee * 2);       // 3 MB
  bf16*  whhHi = (bf16*)alloc((size_t)G3c * Hh * 2);       // 6 MB
  bf16*  whhLo = (bf16*)alloc((size_t)G3c * Hh * 2);       // 6 MB
  bf16*  xeB   = (bf16*)alloc((size_t)TBm * Ee * 2);       // 2 MB
  float* gates = (float*)alloc((size_t)TBm * G3c * 4);     // 25 MB
  float* hseq  = (float*)alloc((size_t)Tt * Bb * Hh * 4);  // 8 MB
  bf16*  hHi0  = (bf16*)alloc((size_t)Bb * Hh * 2);
  bf16*  hHi1  = (bf16*)alloc((size_t)Bb * Hh * 2);
  bf16*  hLo0  = (bf16*)alloc((size_t)Bb * Hh * 2);
  bf16*  hLo1  = (bf16*)alloc((size_t)Bb * Hh * 2);
  float* feat  = gates;  // alias: gates dead after GRU; 16 MB <= 25 MB
  bf16*  featB = (bf16*)alloc((size_t)TBm * FFc * 2);      // 8 MB
  float* Y     = (float*)alloc((size_t)TBm * Hh * 4);      // 8 MB
  bf16*  ybB   = (bf16*)alloc((size_t)TBm * Hh * 2);       // 4 MB

  // ---- weight prep (bf16 conversions / transposes) ----
  cvt_simple_k<<<1024, 256, 0, stream>>>(w_ih, wihB, G3c * Ee);
  cvt_split_k<<<2048, 256, 0, stream>>>(w_hh, whhHi, whhLo, G3c * Hh);
  transpose_cvt_k<<<dim3(Hh / 32, FFc / 32), 256, 0, stream>>>(W1, W1t, FFc, Hh);
  transpose_cvt_k<<<dim3(Vv / 32, Hh / 32), 256, 0, stream>>>(W2, W2t, Hh, Vv);
  embed_k<<<TBm, 128, 0, stream>>>(emb, label, xeB);
  cvt_split_k<<<256, 256, 0, stream>>>(h0, hHi0, hLo0, Bb * Hh);

  // ---- gates_x = x_emb @ w_ih^T + b_ih  [TB, 3H] ----
  gemm_nt_k<0><<<dim3(G3c / 128, TBm / 128), 256, 0, stream>>>(
      xeB, wihB, b_ih, gates, TBm, G3c, Ee);

  // ---- sequential GRU ----
  const bf16* phi[2] = {hHi0, hHi1};
  const bf16* plo[2] = {hLo0, hLo1};
  for (int t = 0; t < Tt; ++t) {
    const float* hp = (t == 0) ? h0 : (hseq + (size_t)(t - 1) * Bb * Hh);
    gru_step_k<<<Hh / 16, 256, 0, stream>>>(
        phi[t & 1], plo[t & 1], whhHi, whhLo, gates, b_hh, hp,
        hseq + (size_t)t * Bb * Hh,
        (bf16*)phi[(t + 1) & 1], (bf16*)plo[(t + 1) & 1], t);
  }

  // ---- batched post-recurrence pipeline ----
  attn_k<<<TBm, 256, 0, stream>>>(hseq, enc, feat);
  bn_k<<<dim3(FFc / 256, Tt), 256, 0, stream>>>(feat, bn1g, bn1b, featB, FFc);
  gemm_nt_k<1><<<dim3(Hh / 128, TBm / 128), 256, 0, stream>>>(
      featB, W1t, b1, Y, TBm, Hh, FFc);
  bn_k<<<dim3(Hh / 256, Tt), 256, 0, stream>>>(Y, bn2g, bn2b, ybB, Hh);
  gemm_nt_k<2><<<dim3(Vv / 128, TBm / 128), 256, 0, stream>>>(
      ybB, W2t, b2, out, TBm, Vv, Hh);
  softmax_k<<<TBm, 256, 0, stream>>>(out);
  hlast_k<<<(Bb * Hh) / 256, 256, 0, stream>>>(
      hseq + (size_t)(Tt - 1) * Bb * Hh, out + (size_t)Bb * Tt * Vv);
}

// Round 2
// 1737.022 us; speedup vs baseline: 1.0461x; 1.0461x over previous
//
#include <hip/hip_runtime.h>

typedef __bf16 bf16;
typedef bf16 bf16x8 __attribute__((ext_vector_type(8)));
typedef float f32x4 __attribute__((ext_vector_type(4)));

#define Vv 32000
#define Ee 512
#define Hh 1024
#define Bb 64
#define Ssz 64
#define Tt 32
#define TBm 2048
#define FFc 2048
#define G3c 3072

__device__ __forceinline__ float sigm(float x) { return 1.f / (1.f + expf(-x)); }

__device__ __forceinline__ void gload16(const void* g, void* l) {
  __builtin_amdgcn_global_load_lds(
      (const __attribute__((address_space(1))) void*)g,
      (__attribute__((address_space(3))) void*)l, 16, 0, 0);
}

__global__ void cvt_simple_k(const float* __restrict__ s, bf16* __restrict__ d, int n) {
  int stride = gridDim.x * blockDim.x;
  for (int i = blockIdx.x * blockDim.x + threadIdx.x; i < n; i += stride)
    d[i] = (bf16)s[i];
}

__global__ void cvt_split_k(const float* __restrict__ s, bf16* __restrict__ hi,
                            bf16* __restrict__ lo, int n) {
  int stride = gridDim.x * blockDim.x;
  for (int i = blockIdx.x * blockDim.x + threadIdx.x; i < n; i += stride) {
    float v = s[i];
    bf16 h = (bf16)v;
    hi[i] = h;
    lo[i] = (bf16)(v - (float)h);
  }
}

// src[R][C] f32 -> dst[C][R] bf16
__global__ void transpose_cvt_k(const float* __restrict__ src, bf16* __restrict__ dst,
                                int R, int C) {
  __shared__ float tile[32][33];
  int bx = blockIdx.x * 32;  // C offset
  int by = blockIdx.y * 32;  // R offset
  int tx = threadIdx.x & 31, ty = threadIdx.x >> 5;
#pragma unroll
  for (int i = 0; i < 4; ++i) {
    int r = ty + i * 8;
    tile[r][tx] = src[(size_t)(by + r) * C + bx + tx];
  }
  __syncthreads();
#pragma unroll
  for (int i = 0; i < 4; ++i) {
    int r = ty + i * 8;
    dst[(size_t)(bx + r) * R + by + tx] = (bf16)tile[tx][r];
  }
}

__global__ void embed_k(const float* __restrict__ emb, const int* __restrict__ label,
                        bf16* __restrict__ xe) {
  int m = blockIdx.x;          // m = t*64 + b
  int t = m >> 6, b = m & 63;
  int tok = (t == 0) ? 1 : label[b * Tt + t - 1];
  const float* src = emb + (size_t)tok * Ee;
  bf16* dst = xe + (size_t)m * Ee;
  for (int e = threadIdx.x; e < Ee; e += blockDim.x) dst[e] = (bf16)src[e];
}

// C[m,n] = sum_k A[m,k]*Bt[n,k] + bias[n]; NT layout, bf16 in, f32 out.
// m97-structure: global_load_lds width-16 staging, 2-barrier K loop,
// XCD-aware block swizzle (m-fastest within per-XCD chunk for B-panel reuse).
// MODE 0: plain write  MODE 1: ELU  MODE 2: scatter to d_out[b*T*V + t*V + n]
template <int MODE>
__global__ void __launch_bounds__(256) gemm_nt_k(
    const bf16* __restrict__ A, const bf16* __restrict__ Bt,
    const float* __restrict__ bias, float* __restrict__ C,
    int M, int N, int K) {
  __shared__ bf16 As[128 * 32];
  __shared__ bf16 Bs[128 * 32];
  const int tid = threadIdx.x;
  const int wv = tid >> 6, ln = tid & 63;
  const int wr = wv >> 1, wc = wv & 1;
  const int l15 = ln & 15, l4 = ln >> 4;

  // XCD swizzle: contiguous virt-chunk per XCD, m fastest (B-tile reuse in L2)
  int NX = gridDim.x, NY = gridDim.y;
  int nwg = NX * NY;
  int lin = blockIdx.x + blockIdx.y * NX;
  int bx, by;
  if ((nwg & 7) == 0) {
    int per = nwg >> 3;
    int virt = (lin & 7) * per + (lin >> 3);
    by = virt % NY;
    bx = virt / NY;
  } else {
    bx = blockIdx.x;
    by = blockIdx.y;
  }
  const int m0 = by * 128, n0 = bx * 128;

  const f32x4 vzero = {0.f, 0.f, 0.f, 0.f};
  f32x4 acc[4][4];
#pragma unroll
  for (int i = 0; i < 4; ++i) {
#pragma unroll
    for (int j = 0; j < 4; ++j) acc[i][j] = vzero;
  }

  const int nk = K >> 5;
  for (int kt = 0; kt < nk; ++kt) {
    const int k0 = kt << 5;
    __syncthreads();  // prior tile's ds_reads done before overwrite
#pragma unroll
    for (int it = 0; it < 2; ++it) {
      int c = tid + it * 256;
      int row = c >> 2, kc = (c & 3) << 3;
      gload16(A + (size_t)(m0 + row) * K + k0 + kc, (char*)As + (size_t)c * 16);
      gload16(Bt + (size_t)(n0 + row) * K + k0 + kc, (char*)Bs + (size_t)c * 16);
    }
    __syncthreads();  // implicit vmcnt(0) drain: staged data visible
    bf16x8 af[4], bfv[4];
#pragma unroll
    for (int mt = 0; mt < 4; ++mt)
      af[mt] = *(const bf16x8*)&As[(wr * 64 + mt * 16 + l15) * 32 + l4 * 8];
#pragma unroll
    for (int nt = 0; nt < 4; ++nt)
      bfv[nt] = *(const bf16x8*)&Bs[(wc * 64 + nt * 16 + l15) * 32 + l4 * 8];
#pragma unroll
    for (int mt = 0; mt < 4; ++mt) {
#pragma unroll
      for (int nt = 0; nt < 4; ++nt)
        acc[mt][nt] = __builtin_amdgcn_mfma_f32_16x16x32_bf16(af[mt], bfv[nt], acc[mt][nt], 0, 0, 0);
    }
  }

#pragma unroll
  for (int mt = 0; mt < 4; ++mt) {
#pragma unroll
    for (int nt = 0; nt < 4; ++nt) {
      int col = wc * 64 + nt * 16 + l15;
      int n = n0 + col;
      float bv = bias[n];
#pragma unroll
      for (int r = 0; r < 4; ++r) {
        int row = wr * 64 + mt * 16 + l4 * 4 + r;
        int m = m0 + row;
        float v = acc[mt][nt][r] + bv;
        if (MODE == 1) v = (v > 0.f) ? v : expm1f(v);
        if (MODE == 2) {
          size_t idx = (size_t)(m & 63) * ((size_t)Tt * Vv) + (size_t)(m >> 6) * Vv + (size_t)n;
          C[idx] = v;
        } else {
          C[(size_t)m * N + n] = v;
        }
      }
    }
  }
}

// One GRU step: gh = h @ w_hh^T (split-bf16, 3 MFMAs per product).
// 64 blocks x 512 threads: block owns 16 j-cols; wave wv: btile=wv&3 owns
// b-rows [btile*16,+16), khalf=wv>>2 owns K half. LDS-reduce K halves,
// gate math in waves 0-3.
__global__ void __launch_bounds__(512) gru_step_k(
    const bf16* __restrict__ hhi, const bf16* __restrict__ hlo,
    const bf16* __restrict__ whhHi, const bf16* __restrict__ whhLo,
    const float* __restrict__ gates, const float* __restrict__ bhh,
    const float* __restrict__ hprev, float* __restrict__ hseq_t,
    bf16* __restrict__ nhi, bf16* __restrict__ nlo, int t) {
  __shared__ float sred[4][3][256];
  const int tid = threadIdx.x;
  const int wv = tid >> 6, ln = tid & 63;
  const int btile = wv & 3, khalf = wv >> 2;
  const int l15 = ln & 15, l4 = ln >> 4;
  const int j0 = blockIdx.x * 16;

  const f32x4 vzero = {0.f, 0.f, 0.f, 0.f};
  f32x4 acc[3] = {vzero, vzero, vzero};
  const int b_a = btile * 16 + l15;
  const int kbase = khalf * 512;
#pragma unroll 2
  for (int kk = 0; kk < 16; ++kk) {
    int k = kbase + kk * 32 + l4 * 8;
    bf16x8 ahi = *(const bf16x8*)(hhi + (size_t)b_a * Hh + k);
    bf16x8 alo = *(const bf16x8*)(hlo + (size_t)b_a * Hh + k);
#pragma unroll
    for (int g = 0; g < 3; ++g) {
      size_t nrow = (size_t)(g * Hh + j0 + l15) * Hh + k;
      bf16x8 bhi = *(const bf16x8*)(whhHi + nrow);
      bf16x8 blo = *(const bf16x8*)(whhLo + nrow);
      acc[g] = __builtin_amdgcn_mfma_f32_16x16x32_bf16(ahi, bhi, acc[g], 0, 0, 0);
      acc[g] = __builtin_amdgcn_mfma_f32_16x16x32_bf16(ahi, blo, acc[g], 0, 0, 0);
      acc[g] = __builtin_amdgcn_mfma_f32_16x16x32_bf16(alo, bhi, acc[g], 0, 0, 0);
    }
  }
  if (khalf == 1) {
#pragma unroll
    for (int g = 0; g < 3; ++g) *(f32x4*)&sred[btile][g][ln * 4] = acc[g];
  }
  __syncthreads();
  if (khalf == 0) {
#pragma unroll
    for (int g = 0; g < 3; ++g) acc[g] += *(const f32x4*)&sred[btile][g][ln * 4];
    int j = j0 + l15;
    float bhr = bhh[j], bhz = bhh[Hh + j], bhn = bhh[2 * Hh + j];
#pragma unroll
    for (int r = 0; r < 4; ++r) {
      int b = btile * 16 + l4 * 4 + r;
      const float* gx = gates + (size_t)(t * Bb + b) * G3c;
      float rg = sigm(gx[j] + acc[0][r] + bhr);
      float zg = sigm(gx[Hh + j] + acc[1][r] + bhz);
      float ng = tanhf(gx[2 * Hh + j] + rg * (acc[2][r] + bhn));
      float hp = hprev[(size_t)b * Hh + j];
      float hv = (1.f - zg) * ng + zg * hp;
      hseq_t[(size_t)b * Hh + j] = hv;
      bf16 hb = (bf16)hv;
      nhi[(size_t)b * Hh + j] = hb;
      nlo[(size_t)b * Hh + j] = (bf16)(hv - (float)hb);
    }
  }
}

// dot attention + feat=concat(h,ctx). One block per (t,b).
__global__ void __launch_bounds__(256) attn_k(
    const float* __restrict__ hseq, const float* __restrict__ enc,
    float* __restrict__ feat) {
  __shared__ float red[256];
  __shared__ float wsm[Ssz];
  int m = blockIdx.x;
  int t = m >> 6, b = m & 63;
  const float* hv = hseq + (size_t)t * Bb * Hh + (size_t)b * Hh;
  const float* eb = enc + (size_t)b * Ssz * Hh;
  int tid = threadIdx.x;
  int s = tid >> 2, q = tid & 3;
  const float* er = eb + (size_t)s * Hh + q * 256;
  const float* hq = hv + q * 256;
  float p = 0.f;
#pragma unroll 4
  for (int i = 0; i < 256; i += 4) {
    float4 a = *(const float4*)(hq + i);
    float4 c = *(const float4*)(er + i);
    p += a.x * c.x + a.y * c.y + a.z * c.z + a.w * c.w;
  }
  red[tid] = p;
  __syncthreads();
  if (tid < 64) {
    float sc = red[tid * 4] + red[tid * 4 + 1] + red[tid * 4 + 2] + red[tid * 4 + 3];
    float mx = sc;
#pragma unroll
    for (int off = 32; off > 0; off >>= 1) mx = fmaxf(mx, __shfl_xor(mx, off));
    float e = expf(sc - mx);
    float sm = e;
#pragma unroll
    for (int off = 32; off > 0; off >>= 1) sm += __shfl_xor(sm, off);
    wsm[tid] = e / sm;
  }
  __syncthreads();
  float* fr = feat + (size_t)m * FFc;
  for (int h = tid; h < Hh; h += 256) {
    float a = 0.f;
#pragma unroll 8
    for (int si = 0; si < Ssz; ++si) a = fmaf(wsm[si], eb[(size_t)si * Hh + h], a);
    fr[Hh + h] = a;
    fr[h] = hv[h];
  }
}

// training-mode BN over batch dim (per t). grid (CH/256, T)
__global__ void __launch_bounds__(256) bn_k(
    const float* __restrict__ x, const float* __restrict__ gam,
    const float* __restrict__ bet, bf16* __restrict__ y, int CH) {
  int t = blockIdx.y;
  int c = blockIdx.x * 256 + threadIdx.x;
  const float* xp = x + (size_t)t * Bb * CH + c;
  float v[Bb];
  float s = 0.f, ss = 0.f;
#pragma unroll
  for (int b = 0; b < Bb; ++b) {
    float u = xp[(size_t)b * CH];
    v[b] = u;
    s += u;
    ss += u * u;
  }
  float mean = s * (1.f / Bb);
  float var = ss * (1.f / Bb) - mean * mean;
  float inv = rsqrtf(var + 1e-5f);
  float sc = gam[c] * inv;
  float sh = bet[c] - mean * sc;
  bf16* yp = y + (size_t)t * Bb * CH + c;
#pragma unroll
  for (int b = 0; b < Bb; ++b) yp[(size_t)b * CH] = (bf16)(v[b] * sc + sh);
}

// in-place row softmax over V. block per (t,b) row of d_out.
__global__ void __launch_bounds__(256) softmax_k(float* __restrict__ out) {
  __shared__ float rm[256], rs[256];
  int m = blockIdx.x;
  int t = m >> 6, b = m & 63;
  float* row = out + (size_t)b * Tt * Vv + (size_t)t * Vv;
  int tid = threadIdx.x;
  float mx = -3.0e38f, sm = 0.f;
  for (int i = tid * 4; i < Vv; i += 1024) {
    float4 v = *(const float4*)(row + i);
    float m4 = fmaxf(fmaxf(v.x, v.y), fmaxf(v.z, v.w));
    if (m4 > mx) { sm *= expf(mx - m4); mx = m4; }
    sm += expf(v.x - mx) + expf(v.y - mx) + expf(v.z - mx) + expf(v.w - mx);
  }
  rm[tid] = mx;
  rs[tid] = sm;
  __syncthreads();
  for (int off = 128; off > 0; off >>= 1) {
    if (tid < off) {
      float ma = rm[tid], mb = rm[tid + off];
      float m2 = fmaxf(ma, mb);
      rs[tid] = rs[tid] * expf(ma - m2) + rs[tid + off] * expf(mb - m2);
      rm[tid] = m2;
    }
    __syncthreads();
  }
  float M = rm[0];
  float inv = 1.f / rs[0];
  for (int i = tid * 4; i < Vv; i += 1024) {
    float4 v = *(const float4*)(row + i);
    v.x = expf(v.x - M) * inv;
    v.y = expf(v.y - M) * inv;
    v.z = expf(v.z - M) * inv;
    v.w = expf(v.w - M) * inv;
    *(float4*)(row + i) = v;
  }
}

__global__ void hlast_k(const float* __restrict__ src, float* __restrict__ dst) {
  int i = blockIdx.x * 256 + threadIdx.x;
  dst[i] = src[i];
}

extern "C" void kernel_launch(void* const* d_in, const int* in_sizes, int n_in,
                              void* d_out, int out_size, void* d_ws, size_t ws_size,
                              hipStream_t stream) {
  const float* enc   = (const float*)d_in[0];
  const int*   label = (const int*)d_in[1];
  const float* h0    = (const float*)d_in[2];
  // d_in[3] answer_lens: unused by the forward pass
  const float* emb   = (const float*)d_in[4];
  const float* w_ih  = (const float*)d_in[5];
  const float* w_hh  = (const float*)d_in[6];
  const float* b_ih  = (const float*)d_in[7];
  const float* b_hh  = (const float*)d_in[8];
  const float* bn1g  = (const float*)d_in[9];
  const float* bn1b  = (const float*)d_in[10];
  const float* W1    = (const float*)d_in[11];
  const float* b1    = (const float*)d_in[12];
  const float* bn2g  = (const float*)d_in[13];
  const float* bn2b  = (const float*)d_in[14];
  const float* W2    = (const float*)d_in[15];
  const float* b2    = (const float*)d_in[16];
  float* out = (float*)d_out;
  (void)in_sizes; (void)n_in; (void)out_size; (void)ws_size;

  char* ws = (char*)d_ws;
  size_t off = 0;
  auto alloc = [&](size_t bytes) -> void* {
    void* p = ws + off;
    off += (bytes + 255) & ~(size_t)255;
    return p;
  };
  bf16*  W2t   = (bf16*)alloc((size_t)Vv * Hh * 2);        // 64 MB
  bf16*  W1t   = (bf16*)alloc((size_t)Hh * FFc * 2);       // 4 MB
  bf16*  wihB  = (bf16*)alloc((size_t)G3c * Ee * 2);       // 3 MB
  bf16*  whhHi = (bf16*)alloc((size_t)G3c * Hh * 2);       // 6 MB
  bf16*  whhLo = (bf16*)alloc((size_t)G3c * Hh * 2);       // 6 MB
  bf16*  xeB   = (bf16*)alloc((size_t)TBm * Ee * 2);       // 2 MB
  float* gates = (float*)alloc((size_t)TBm * G3c * 4);     // 25 MB
  float* hseq  = (float*)alloc((size_t)Tt * Bb * Hh * 4);  // 8 MB
  bf16*  hHi0  = (bf16*)alloc((size_t)Bb * Hh * 2);
  bf16*  hHi1  = (bf16*)alloc((size_t)Bb * Hh * 2);
  bf16*  hLo0  = (bf16*)alloc((size_t)Bb * Hh * 2);
  bf16*  hLo1  = (bf16*)alloc((size_t)Bb * Hh * 2);
  float* feat  = gates;  // alias: gates dead after GRU; 16 MB <= 25 MB
  bf16*  featB = (bf16*)alloc((size_t)TBm * FFc * 2);      // 8 MB
  float* Y     = (float*)alloc((size_t)TBm * Hh * 4);      // 8 MB
  bf16*  ybB   = (bf16*)alloc((size_t)TBm * Hh * 2);       // 4 MB

  // ---- weight prep (bf16 conversions / transposes) ----
  cvt_simple_k<<<1024, 256, 0, stream>>>(w_ih, wihB, G3c * Ee);
  cvt_split_k<<<2048, 256, 0, stream>>>(w_hh, whhHi, whhLo, G3c * Hh);
  transpose_cvt_k<<<dim3(Hh / 32, FFc / 32), 256, 0, stream>>>(W1, W1t, FFc, Hh);
  transpose_cvt_k<<<dim3(Vv / 32, Hh / 32), 256, 0, stream>>>(W2, W2t, Hh, Vv);
  embed_k<<<TBm, 128, 0, stream>>>(emb, label, xeB);
  cvt_split_k<<<256, 256, 0, stream>>>(h0, hHi0, hLo0, Bb * Hh);

  // ---- gates_x = x_emb @ w_ih^T + b_ih  [TB, 3H] ----
  gemm_nt_k<0><<<dim3(G3c / 128, TBm / 128), 256, 0, stream>>>(
      xeB, wihB, b_ih, gates, TBm, G3c, Ee);

  // ---- sequential GRU ----
  const bf16* phi[2] = {hHi0, hHi1};
  const bf16* plo[2] = {hLo0, hLo1};
  for (int t = 0; t < Tt; ++t) {
    const float* hp = (t == 0) ? h0 : (hseq + (size_t)(t - 1) * Bb * Hh);
    gru_step_k<<<Hh / 16, 512, 0, stream>>>(
        phi[t & 1], plo[t & 1], whhHi, whhLo, gates, b_hh, hp,
        hseq + (size_t)t * Bb * Hh,
        (bf16*)phi[(t + 1) & 1], (bf16*)plo[(t + 1) & 1], t);
  }

  // ---- batched post-recurrence pipeline ----
  attn_k<<<TBm, 256, 0, stream>>>(hseq, enc, feat);
  bn_k<<<dim3(FFc / 256, Tt), 256, 0, stream>>>(feat, bn1g, bn1b, featB, FFc);
  gemm_nt_k<1><<<dim3(Hh / 128, TBm / 128), 256, 0, stream>>>(
      featB, W1t, b1, Y, TBm, Hh, FFc);
  bn_k<<<dim3(Hh / 256, Tt), 256, 0, stream>>>(Y, bn2g, bn2b, ybB, Hh);
  gemm_nt_k<2><<<dim3(Vv / 128, TBm / 128), 256, 0, stream>>>(
      ybB, W2t, b2, out, TBm, Vv, Hh);
  softmax_k<<<TBm, 256, 0, stream>>>(out);
  hlast_k<<<(Bb * Hh) / 256, 256, 0, stream>>>(
      hseq + (size_t)(Tt - 1) * Bb * Hh, out + (size_t)Bb * Tt * Vv);
}